// Round 14
// baseline (386.093 us; speedup 1.0000x reference)
//
#include <hip/hip_runtime.h>
#include <hip/hip_fp16.h>

#define TPB 256
#define CAP 32          // fixed CSR slots per node (Poisson(16): P(deg>32) ~ 3e-5)
#define OVFCAP 65536    // overflow list capacity (expected usage ~tens)

typedef __attribute__((ext_vector_type(8))) short bf16x8;
typedef __attribute__((ext_vector_type(4))) float f32x4;

// ---------- fp32 -> bf16 hi/lo split ----------
__device__ inline void split1(float x, unsigned short& h, unsigned short& l) {
  unsigned xb = __float_as_uint(x);
  h = (unsigned short)(xb >> 16);
  float hf = __uint_as_float(xb & 0xFFFF0000u);
  float lf = x - hf;
  l = (unsigned short)(__float_as_uint(lf) >> 16);
}

__device__ inline void split4(const float4 v, ushort4& h, ushort4& l) {
  split1(v.x, h.x, l.x);
  split1(v.y, h.y, l.y);
  split1(v.z, h.z, l.z);
  split1(v.w, h.w, l.w);
}

// ---------- FUSED: CSR fill (atomic-bound) || GEMM1 (MFMA-bound) ----------
// Block roles interleaved in groups of 8 so BOTH roles cover all 8 XCDs
// (parity interleave would pin fill to odd XCDs and halve atomic throughput).
// Fill role: identical single-pass fixed-slot CSR build (1 RMW/edge floor).
// GEMM role: layer-1 MFMA GEMM, output UNscaled fp16 (dinv not ready yet;
// a cheap k_scale16 pass applies it afterwards). Disjoint resources overlap.
__launch_bounds__(512)
__global__ void k_fused1(const float* __restrict__ X, const unsigned short* __restrict__ Wh,
                         const unsigned short* __restrict__ Wl,
                         const int* __restrict__ src, const int* __restrict__ dst,
                         int* __restrict__ cnt, int* __restrict__ col2,
                         uint2* __restrict__ ovf, int* __restrict__ ovfn,
                         __half* __restrict__ Y16, int E, int N, int nT) {
  constexpr int K = 128, BM = 128, COUT = 128, WCOL = 64, NFRAG = 4;
  __shared__ unsigned short Ah[BM * K], Al[BM * K];
  __shared__ unsigned short Wsh[COUT * K], Wsl[COUT * K];

  const int grp = blockIdx.x >> 3, l8 = blockIdx.x & 7;

  if (grp & 1) {
    // ---- fill role: 1024 virtual blocks x 512 threads ----
    const int fid = (grp >> 1) * 8 + l8;        // 0..1023
    const int g = fid & 7, gb = fid >> 3;       // 8 node groups x 128 blocks
    const int gstride = 128 * 512;
    const int lo = (int)(((long long)g * N) >> 3);
    const int hi = (int)(((long long)(g + 1) * N) >> 3);
    for (int e = gb * 512 + threadIdx.x; e < E; e += gstride) {
      int d = __builtin_nontemporal_load(dst + e);
      if (d >= lo && d < hi) {
        int s = __builtin_nontemporal_load(src + e);
        int c = atomicAdd(cnt + d, 1);
        if (c < CAP) {
          col2[(size_t)d * CAP + c] = s;
        } else {
          int p = atomicAdd(ovfn, 1);
          if (p < OVFCAP) ovf[p] = make_uint2((unsigned)d, (unsigned)s);
        }
      }
    }
    return;
  }

  // ---- gemm role ----
  const int tile = (grp >> 1) * 8 + l8;
  if (tile >= nT) return;
  const int tid = threadIdx.x;
  const int rb = tile * BM;

  {
    const uint4* gh = (const uint4*)Wh;
    const uint4* gl = (const uint4*)Wl;
    for (int i = tid; i < COUT * 16; i += 512) {
      int r = i >> 4, c = i & 15;
      int byte = r * 256 + ((c * 16) ^ ((r & 7) << 4));
      *(uint4*)((char*)Wsh + byte) = gh[i];
      *(uint4*)((char*)Wsl + byte) = gl[i];
    }
  }
  {
    for (int i = tid; i < BM * 32; i += 512) {
      int r = i >> 5, c4 = i & 31;
      int gr = rb + r;
      if (gr < N) {
        float4 v = ((const float4*)(X + (size_t)gr * K))[c4];
        ushort4 h, l;
        split4(v, h, l);
        int byte = r * 256 + ((c4 * 8) ^ ((r & 7) << 4));
        *(ushort4*)((char*)Ah + byte) = h;
        *(ushort4*)((char*)Al + byte) = l;
      }
    }
  }
  __syncthreads();

  const int wid = tid >> 6, lane = tid & 63;
  const int wm = wid & 3;
  const int wn = wid >> 2;
  const int RB = wm * 32;
  const int CB = wn * WCOL;
  const int l15 = lane & 15, l4 = lane >> 4;
  const int xs = (l15 & 7) << 4;

  f32x4 acc[2][NFRAG];
  #pragma unroll
  for (int m = 0; m < 2; ++m)
    #pragma unroll
    for (int n = 0; n < NFRAG; ++n)
      acc[m][n] = (f32x4){0.f, 0.f, 0.f, 0.f};

  #pragma unroll
  for (int ks = 0; ks < 4; ++ks) {
    const int cbx = (ks * 64 + l4 * 16) ^ xs;
    bf16x8 a0h = *(const bf16x8*)((const char*)Ah + (RB + l15) * 256 + cbx);
    bf16x8 a0l = *(const bf16x8*)((const char*)Al + (RB + l15) * 256 + cbx);
    bf16x8 a1h = *(const bf16x8*)((const char*)Ah + (RB + 16 + l15) * 256 + cbx);
    bf16x8 a1l = *(const bf16x8*)((const char*)Al + (RB + 16 + l15) * 256 + cbx);
    #pragma unroll
    for (int n = 0; n < NFRAG; ++n) {
      const int wr = CB + n * 16 + l15;
      bf16x8 bh = *(const bf16x8*)((const char*)Wsh + wr * 256 + cbx);
      bf16x8 bl = *(const bf16x8*)((const char*)Wsl + wr * 256 + cbx);
      acc[0][n] = __builtin_amdgcn_mfma_f32_16x16x32_bf16(a0h, bh, acc[0][n], 0, 0, 0);
      acc[0][n] = __builtin_amdgcn_mfma_f32_16x16x32_bf16(a0h, bl, acc[0][n], 0, 0, 0);
      acc[0][n] = __builtin_amdgcn_mfma_f32_16x16x32_bf16(a0l, bh, acc[0][n], 0, 0, 0);
      acc[1][n] = __builtin_amdgcn_mfma_f32_16x16x32_bf16(a1h, bh, acc[1][n], 0, 0, 0);
      acc[1][n] = __builtin_amdgcn_mfma_f32_16x16x32_bf16(a1h, bl, acc[1][n], 0, 0, 0);
      acc[1][n] = __builtin_amdgcn_mfma_f32_16x16x32_bf16(a1l, bh, acc[1][n], 0, 0, 0);
    }
  }

  #pragma unroll
  for (int m = 0; m < 2; ++m) {
    #pragma unroll
    for (int q = 0; q < 4; ++q) {
      int row = rb + RB + m * 16 + l4 * 4 + q;
      if (row < N) {
        __half* yr = Y16 + (size_t)row * COUT + CB + l15;
        #pragma unroll
        for (int n = 0; n < NFRAG; ++n) yr[n * 16] = __float2half(acc[m][n][q]);
      }
    }
  }
}

__global__ void k_dinv_from_cnt(const int* __restrict__ cnt, float* __restrict__ dinv, int N) {
  int i = blockIdx.x * blockDim.x + threadIdx.x;
  if (i < N) dinv[i] = rsqrtf((float)(cnt[i] + 1));
}

// ---------- H16 *= dinv[row]  (applies deferred layer-1 scaling) ----------
__global__ void k_scale16(__half* __restrict__ H, const float* __restrict__ dinv, int total16) {
  int i = blockIdx.x * blockDim.x + threadIdx.x;   // one per 8 halves (16B)
  if (i >= total16) return;
  float dv = dinv[i >> 4];                         // 16 chunks per 128-col row
  uint4* p = (uint4*)H + i;
  uint4 v = *p;
  __half2* h2 = (__half2*)&v;
  #pragma unroll
  for (int q = 0; q < 4; ++q) {
    float2 f = __half22float2(h2[q]);
    f.x *= dv; f.y *= dv;
    h2[q] = __float22half2_rn(f);
  }
  *p = v;
}

// ---------- W prep: both weights in one launch ----------
__global__ void k_prep_wt2(const float* __restrict__ W1, unsigned short* __restrict__ W1h,
                           unsigned short* __restrict__ W1l, int K1, int C1,
                           const float* __restrict__ W2, unsigned short* __restrict__ W2h,
                           unsigned short* __restrict__ W2l, int K2, int C2) {
  int i = blockIdx.x * blockDim.x + threadIdx.x;
  int n1 = K1 * C1;
  if (i < n1) {
    int k = i / C1, c = i % C1;
    unsigned short h, l;
    split1(W1[i], h, l);
    W1h[(size_t)c * K1 + k] = h;
    W1l[(size_t)c * K1 + k] = l;
  } else if (i < n1 + K2 * C2) {
    int ii = i - n1;
    int k = ii / C2, c = ii % C2;
    unsigned short h, l;
    split1(W2[ii], h, l);
    W2h[(size_t)c * K2 + k] = h;
    W2l[(size_t)c * K2 + k] = l;
  }
}

// ---------- MFMA GEMM (layer 2): Y16 = fp16((X @ W) * dinv[row]) ----------
template<int COUT>
__launch_bounds__(512)
__global__ void k_gemm_mfma(const float* __restrict__ X, const unsigned short* __restrict__ Wh,
                            const unsigned short* __restrict__ Wl, const float* __restrict__ dinv,
                            __half* __restrict__ Y16, int N) {
  constexpr int K = 128;
  constexpr int BM = 128;
  constexpr int WCOL = COUT / 2;
  constexpr int NFRAG = WCOL / 16;
  __shared__ unsigned short Ah[BM * K], Al[BM * K];
  __shared__ unsigned short Wsh[COUT * K], Wsl[COUT * K];

  const int tid = threadIdx.x;
  const int rb = blockIdx.x * BM;

  {
    const uint4* gh = (const uint4*)Wh;
    const uint4* gl = (const uint4*)Wl;
    for (int i = tid; i < COUT * 16; i += 512) {
      int r = i >> 4, c = i & 15;
      int byte = r * 256 + ((c * 16) ^ ((r & 7) << 4));
      *(uint4*)((char*)Wsh + byte) = gh[i];
      *(uint4*)((char*)Wsl + byte) = gl[i];
    }
  }
  {
    for (int i = tid; i < BM * 32; i += 512) {
      int r = i >> 5, c4 = i & 31;
      int g = rb + r;
      if (g < N) {
        float4 v = ((const float4*)(X + (size_t)g * K))[c4];
        ushort4 h, l;
        split4(v, h, l);
        int byte = r * 256 + ((c4 * 8) ^ ((r & 7) << 4));
        *(ushort4*)((char*)Ah + byte) = h;
        *(ushort4*)((char*)Al + byte) = l;
      }
    }
  }
  __syncthreads();

  const int wid = tid >> 6, lane = tid & 63;
  const int wm = wid & 3;
  const int wn = wid >> 2;
  const int RB = wm * 32;
  const int CB = wn * WCOL;
  const int l15 = lane & 15, l4 = lane >> 4;
  const int xs = (l15 & 7) << 4;

  f32x4 acc[2][NFRAG];
  #pragma unroll
  for (int m = 0; m < 2; ++m)
    #pragma unroll
    for (int n = 0; n < NFRAG; ++n)
      acc[m][n] = (f32x4){0.f, 0.f, 0.f, 0.f};

  #pragma unroll
  for (int ks = 0; ks < 4; ++ks) {
    const int cbx = (ks * 64 + l4 * 16) ^ xs;
    bf16x8 a0h = *(const bf16x8*)((const char*)Ah + (RB + l15) * 256 + cbx);
    bf16x8 a0l = *(const bf16x8*)((const char*)Al + (RB + l15) * 256 + cbx);
    bf16x8 a1h = *(const bf16x8*)((const char*)Ah + (RB + 16 + l15) * 256 + cbx);
    bf16x8 a1l = *(const bf16x8*)((const char*)Al + (RB + 16 + l15) * 256 + cbx);
    #pragma unroll
    for (int n = 0; n < NFRAG; ++n) {
      const int wr = CB + n * 16 + l15;
      bf16x8 bh = *(const bf16x8*)((const char*)Wsh + wr * 256 + cbx);
      bf16x8 bl = *(const bf16x8*)((const char*)Wsl + wr * 256 + cbx);
      acc[0][n] = __builtin_amdgcn_mfma_f32_16x16x32_bf16(a0h, bh, acc[0][n], 0, 0, 0);
      acc[0][n] = __builtin_amdgcn_mfma_f32_16x16x32_bf16(a0h, bl, acc[0][n], 0, 0, 0);
      acc[0][n] = __builtin_amdgcn_mfma_f32_16x16x32_bf16(a0l, bh, acc[0][n], 0, 0, 0);
      acc[1][n] = __builtin_amdgcn_mfma_f32_16x16x32_bf16(a1h, bh, acc[1][n], 0, 0, 0);
      acc[1][n] = __builtin_amdgcn_mfma_f32_16x16x32_bf16(a1h, bl, acc[1][n], 0, 0, 0);
      acc[1][n] = __builtin_amdgcn_mfma_f32_16x16x32_bf16(a1l, bh, acc[1][n], 0, 0, 0);
    }
  }

  #pragma unroll
  for (int m = 0; m < 2; ++m) {
    #pragma unroll
    for (int q = 0; q < 4; ++q) {
      int row = rb + RB + m * 16 + l4 * 4 + q;
      if (row < N) {
        float dv = dinv[row];
        __half* yr = Y16 + (size_t)row * COUT + CB + l15;
        #pragma unroll
        for (int n = 0; n < NFRAG; ++n) yr[n * 16] = __float2half(acc[m][n][q] * dv);
      }
    }
  }
}

// ---------- vectorized aggregate: one WAVE per node; int4 index loads ----------
template<int C>
__launch_bounds__(256)
__global__ void k_aggv(const __half* __restrict__ hsh, const float* __restrict__ dinv,
                       const int* __restrict__ cnt, const int* __restrict__ col2,
                       const uint2* __restrict__ ovf, const int* __restrict__ ovfn,
                       const float* __restrict__ bias, float* __restrict__ out, int N) {
  constexpr int LPR = C / 8;           // lanes per row-slice: 16 (C=128) / 8 (C=64)
  constexpr int NG = 64 / LPR;         // neighbor groups: 4 / 8
  constexpr int SPR = 4 * NG;          // slots per round: 16 / 32
  constexpr int NR = CAP / SPR;        // rounds: 2 / 1
  const int node = blockIdx.x * 4 + (threadIdx.x >> 6);
  if (node >= N) return;
  const int lane = threadIdx.x & 63;
  const int i = lane % LPR;
  const int j = lane / LPR;
  const int deg = cnt[node];
  const int m = min(deg, CAP);
  const int4* cp4 = (const int4*)(col2 + (size_t)node * CAP);
  const size_t coloff = (size_t)i * 8;

  float acc[8];
  #pragma unroll
  for (int q = 0; q < 8; ++q) acc[q] = 0.f;

  #pragma unroll
  for (int r = 0; r < NR; ++r) {
    if (r * SPR < m) {                 // wave-uniform (m same across wave)
      int4 idx = cp4[r * NG + j];
      int s0 = r * SPR + 4 * j;
      bool ok0 = s0 + 0 < m, ok1 = s0 + 1 < m, ok2 = s0 + 2 < m, ok3 = s0 + 3 < m;
      int n0 = ok0 ? idx.x : 0;
      int n1 = ok1 ? idx.y : 0;
      int n2 = ok2 ? idx.z : 0;
      int n3 = ok3 ? idx.w : 0;
      uint4 v0 = *(const uint4*)((const char*)hsh + ((size_t)n0 * C + coloff) * 2);
      uint4 v1 = *(const uint4*)((const char*)hsh + ((size_t)n1 * C + coloff) * 2);
      uint4 v2 = *(const uint4*)((const char*)hsh + ((size_t)n2 * C + coloff) * 2);
      uint4 v3 = *(const uint4*)((const char*)hsh + ((size_t)n3 * C + coloff) * 2);
      float f0 = ok0 ? 1.f : 0.f, f1 = ok1 ? 1.f : 0.f;
      float f2 = ok2 ? 1.f : 0.f, f3 = ok3 ? 1.f : 0.f;
      const __half2* h0 = (const __half2*)&v0;
      const __half2* h1 = (const __half2*)&v1;
      const __half2* h2 = (const __half2*)&v2;
      const __half2* h3 = (const __half2*)&v3;
      #pragma unroll
      for (int q = 0; q < 4; ++q) {
        float2 a = __half22float2(h0[q]);
        float2 b = __half22float2(h1[q]);
        float2 c = __half22float2(h2[q]);
        float2 d = __half22float2(h3[q]);
        acc[2 * q]     = fmaf(f0, a.x, acc[2 * q]);
        acc[2 * q + 1] = fmaf(f0, a.y, acc[2 * q + 1]);
        acc[2 * q]     = fmaf(f1, b.x, acc[2 * q]);
        acc[2 * q + 1] = fmaf(f1, b.y, acc[2 * q + 1]);
        acc[2 * q]     = fmaf(f2, c.x, acc[2 * q]);
        acc[2 * q + 1] = fmaf(f2, c.y, acc[2 * q + 1]);
        acc[2 * q]     = fmaf(f3, d.x, acc[2 * q]);
        acc[2 * q + 1] = fmaf(f3, d.y, acc[2 * q + 1]);
      }
    }
  }

  // rare overflow path (deg > CAP): group j==0 scans the tiny overflow list
  if (deg > CAP && j == 0) {
    int on = min(*ovfn, (int)OVFCAP);
    for (int k = 0; k < on; ++k) {
      uint2 eo = ovf[k];
      if ((int)eo.x == node) {
        uint4 v = *(const uint4*)((const char*)hsh + ((size_t)eo.y * C + coloff) * 2);
        const __half2* h2 = (const __half2*)&v;
        #pragma unroll
        for (int q = 0; q < 4; ++q) {
          float2 a = __half22float2(h2[q]);
          acc[2 * q] += a.x;
          acc[2 * q + 1] += a.y;
        }
      }
    }
  }

  #pragma unroll
  for (int off = LPR; off < 64; off <<= 1)
    #pragma unroll
    for (int q = 0; q < 8; ++q)
      acc[q] += __shfl_xor(acc[q], off);

  if (j < 2) {
    const float dv = dinv[node];
    const int f4 = 2 * i + j;
    uint2 sh = *(const uint2*)((const char*)hsh + ((size_t)node * C + (size_t)f4 * 4) * 2);
    const __half2* shh = (const __half2*)&sh;
    float2 s01 = __half22float2(shh[0]);
    float2 s23 = __half22float2(shh[1]);
    float4 bb = ((const float4*)bias)[f4];
    float4 o;
    o.x = fmaxf(fmaf(dv, s01.x + acc[4 * j + 0], bb.x), 0.f);
    o.y = fmaxf(fmaf(dv, s01.y + acc[4 * j + 1], bb.y), 0.f);
    o.z = fmaxf(fmaf(dv, s23.x + acc[4 * j + 2], bb.z), 0.f);
    o.w = fmaxf(fmaf(dv, s23.y + acc[4 * j + 3], bb.w), 0.f);
    ((float4*)(out + (size_t)node * C))[f4] = o;
  }
}

// ---------- fallback (atomic scatter) kernels ----------
__global__ void k_fill1(float* __restrict__ p, int n) {
  int i = blockIdx.x * blockDim.x + threadIdx.x;
  if (i < n) p[i] = 1.0f;
}
__global__ void k_deg_scatter(const int* __restrict__ dst, float* __restrict__ deg, int E) {
  int e = blockIdx.x * blockDim.x + threadIdx.x;
  if (e < E) atomicAdd(deg + dst[e], 1.0f);
}
__global__ void k_rsqrt_inplace(float* __restrict__ p, int n) {
  int i = blockIdx.x * blockDim.x + threadIdx.x;
  if (i < n) p[i] = rsqrtf(p[i]);
}
template<int COUT>
__launch_bounds__(256)
__global__ void k_gemm128(const float* __restrict__ X, const float* __restrict__ W,
                          const float* __restrict__ dinv, float* __restrict__ Y, int N) {
  constexpr int K = 128;
  constexpr int CG = COUT / 8;
  constexpr int ROWS = 256 / CG;
  constexpr int XSTR = K + 4;
  __shared__ float Ws[K * COUT];
  __shared__ float Xs[ROWS * XSTR];
  const int tid = threadIdx.x;

  const float4* W4 = (const float4*)W;
  float4* Ws4 = (float4*)Ws;
  #pragma unroll
  for (int i = tid; i < K * COUT / 4; i += 256) Ws4[i] = W4[i];

  const int rb = blockIdx.x * ROWS;
  float4* Xs4 = (float4*)Xs;
  for (int i = tid; i < ROWS * (K / 4); i += 256) {
    int r = i / (K / 4), c = i % (K / 4);
    float4 v = make_float4(0.f, 0.f, 0.f, 0.f);
    if (rb + r < N) v = ((const float4*)(X + (size_t)(rb + r) * K))[c];
    Xs4[r * (XSTR / 4) + c] = v;
  }
  __syncthreads();

  const int lrow = tid / CG;
  const int cg = tid % CG;
  const int row = rb + lrow;
  float acc[8];
  #pragma unroll
  for (int jj = 0; jj < 8; ++jj) acc[jj] = 0.f;
  const float* xr = Xs + lrow * XSTR;
  #pragma unroll 4
  for (int k = 0; k < K; ++k) {
    float xv = xr[k];
    float4 w0 = Ws4[k * (COUT / 4) + cg * 2];
    float4 w1 = Ws4[k * (COUT / 4) + cg * 2 + 1];
    acc[0] = fmaf(xv, w0.x, acc[0]);
    acc[1] = fmaf(xv, w0.y, acc[1]);
    acc[2] = fmaf(xv, w0.z, acc[2]);
    acc[3] = fmaf(xv, w0.w, acc[3]);
    acc[4] = fmaf(xv, w1.x, acc[4]);
    acc[5] = fmaf(xv, w1.y, acc[5]);
    acc[6] = fmaf(xv, w1.z, acc[6]);
    acc[7] = fmaf(xv, w1.w, acc[7]);
  }
  if (row < N) {
    float ds = dinv[row];
    float4* y = (float4*)(Y + (size_t)row * COUT + cg * 8);
    y[0] = make_float4(acc[0] * ds, acc[1] * ds, acc[2] * ds, acc[3] * ds);
    y[1] = make_float4(acc[4] * ds, acc[5] * ds, acc[6] * ds, acc[7] * ds);
  }
}
template<int C>
__global__ void k_selfinit2(const float* __restrict__ hs, const float* __restrict__ dinv,
                            float* __restrict__ agg, int N) {
  int i = blockIdx.x * blockDim.x + threadIdx.x;
  int total = N * (C / 4);
  if (i >= total) return;
  int node = i / (C / 4);
  float di = dinv[node];
  float4 v = ((const float4*)hs)[i];
  ((float4*)agg)[i] = make_float4(v.x * di, v.y * di, v.z * di, v.w * di);
}
template<int C>
__global__ void k_scatter(const float* __restrict__ hs, const float* __restrict__ dinv,
                          const int* __restrict__ src, const int* __restrict__ dst,
                          float* __restrict__ agg, int E) {
  constexpr int LPE = C / 4;
  long long t = (long long)blockIdx.x * blockDim.x + threadIdx.x;
  int e = (int)(t / LPE);
  if (e >= E) return;
  int c4 = (int)(t % LPE);
  int s = src[e], d = dst[e];
  float nd = dinv[d];
  float4 v = ((const float4*)(hs + (size_t)s * C))[c4];
  float* a = agg + (size_t)d * C + (size_t)c4 * 4;
  atomicAdd(a + 0, v.x * nd);
  atomicAdd(a + 1, v.y * nd);
  atomicAdd(a + 2, v.z * nd);
  atomicAdd(a + 3, v.w * nd);
}
template<int C>
__global__ void k_relu_bias(const float* __restrict__ agg, const float* __restrict__ b,
                            float* __restrict__ out, int N) {
  int i = blockIdx.x * blockDim.x + threadIdx.x;
  int total = N * (C / 4);
  if (i >= total) return;
  int c4 = i % (C / 4);
  float4 bb = ((const float4*)b)[c4];
  float4 v = ((const float4*)agg)[i];
  v.x = fmaxf(v.x + bb.x, 0.f);
  v.y = fmaxf(v.y + bb.y, 0.f);
  v.z = fmaxf(v.z + bb.z, 0.f);
  v.w = fmaxf(v.w + bb.w, 0.f);
  ((float4*)out)[i] = v;
}

extern "C" void kernel_launch(void* const* d_in, const int* in_sizes, int n_in,
                              void* d_out, int out_size, void* d_ws, size_t ws_size,
                              hipStream_t stream) {
  const float* x  = (const float*)d_in[0];
  const int*   ei = (const int*)d_in[1];
  const float* W1 = (const float*)d_in[2];
  const float* b1 = (const float*)d_in[3];
  const float* W2 = (const float*)d_in[4];
  const float* b2 = (const float*)d_in[5];

  const int Cin = 128, Chid = 128, Cout2 = 64;
  const int N = in_sizes[0] / Cin;
  const int E = in_sizes[1] / 2;
  const int* src = ei;
  const int* dst = ei + E;
  float* out = (float*)d_out;
  (void)n_in; (void)out_size;

  const int nbN = (N + TPB - 1) / TPB;
  const int nbE = (E + TPB - 1) / TPB;
  const int nT = (N + 127) / 128;

  auto align = [](size_t v) { return (v + 511) & ~(size_t)511; };
  char* ws = (char*)d_ws;
  size_t off = 0;
  float* dinv   = (float*)(ws + off); off += align((size_t)N * 4);
  int*   cnt    = (int*)(ws + off);   off += align((size_t)N * 4);
  unsigned short* wt1h = (unsigned short*)(ws + off); off += align((size_t)Cin * Chid * 2);
  unsigned short* wt1l = (unsigned short*)(ws + off); off += align((size_t)Cin * Chid * 2);
  unsigned short* wt2h = (unsigned short*)(ws + off); off += align((size_t)Chid * Cout2 * 2);
  unsigned short* wt2l = (unsigned short*)(ws + off); off += align((size_t)Chid * Cout2 * 2);
  int*   col2   = (int*)(ws + off);   off += align((size_t)N * CAP * 4);
  int*   ovfn   = (int*)(ws + off);   off += align((size_t)64);
  uint2* ovf    = (uint2*)(ws + off); off += align((size_t)OVFCAP * 8);
  float* B      = (float*)(ws + off); off += (size_t)N * Chid * 4;
  __half* H16   = (__half*)(ws + off); off += align((size_t)N * Chid * 2);

  const bool fast_ok = (off <= ws_size) && (nT <= 1024);

  if (fast_ok) {
    // ---- build prep ----
    hipMemsetAsync(cnt, 0, (size_t)N * 4, stream);
    hipMemsetAsync(ovfn, 0, 4, stream);
    {
      int total = Cin * Chid + Chid * Cout2;
      k_prep_wt2<<<(total + TPB - 1) / TPB, TPB, 0, stream>>>(
          W1, wt1h, wt1l, Cin, Chid, W2, wt2h, wt2l, Chid, Cout2);
    }

    // ---- FUSED: CSR fill || GEMM1 (unscaled fp16 out) ----
    k_fused1<<<2048, 512, 0, stream>>>(x, wt1h, wt1l, src, dst, cnt, col2, ovf, ovfn,
                                       H16, E, N, nT);

    // ---- dinv + deferred layer-1 scaling ----
    k_dinv_from_cnt<<<nbN, TPB, 0, stream>>>(cnt, dinv, N);
    k_scale16<<<(N * 16 + TPB - 1) / TPB, TPB, 0, stream>>>(H16, dinv, N * 16);

    // ---- layer 1 aggregate ----
    k_aggv<128><<<(N + 3) / 4, 256, 0, stream>>>(H16, dinv, cnt, col2, ovf, ovfn, b1, B, N);
    // ---- layer 2 ----
    k_gemm_mfma<64><<<(N + 127) / 128, 512, 0, stream>>>(B, wt2h, wt2l, dinv, H16, N);
    k_aggv<64><<<(N + 3) / 4, 256, 0, stream>>>(H16, dinv, cnt, col2, ovf, ovfn, b2, out, N);
  } else {
    // ---- fallback: atomic-scatter path ----
    size_t o2 = 0;
    float* dinvF = (float*)(ws + o2); o2 += align((size_t)N * 4);
    float* AF = (float*)(ws + o2);    o2 += (size_t)N * Chid * 4;
    float* BF = (float*)(ws + o2);

    k_fill1<<<nbN, TPB, 0, stream>>>(dinvF, N);
    k_deg_scatter<<<nbE, TPB, 0, stream>>>(dst, dinvF, E);
    k_rsqrt_inplace<<<nbN, TPB, 0, stream>>>(dinvF, N);

    k_gemm128<128><<<(N + 15) / 16, 256, 0, stream>>>(x, W1, dinvF, AF, N);
    k_selfinit2<128><<<(N * 32 + TPB - 1) / TPB, TPB, 0, stream>>>(AF, dinvF, BF, N);
    {
      long long total = (long long)E * 32;
      k_scatter<128><<<(int)((total + TPB - 1) / TPB), TPB, 0, stream>>>(AF, dinvF, src, dst, BF, E);
    }
    k_relu_bias<128><<<(N * 32 + TPB - 1) / TPB, TPB, 0, stream>>>(BF, b1, AF, N);

    k_gemm128<64><<<(N + 31) / 32, 256, 0, stream>>>(AF, W2, dinvF, BF, N);
    k_selfinit2<64><<<(N * 16 + TPB - 1) / TPB, TPB, 0, stream>>>(BF, dinvF, out, N);
    {
      long long total = (long long)E * 16;
      k_scatter<64><<<(int)((total + TPB - 1) / TPB), TPB, 0, stream>>>(BF, dinvF, src, dst, out, E);
    }
    k_relu_bias<64><<<(N * 16 + TPB - 1) / TPB, TPB, 0, stream>>>(out, b2, out, N);
  }
}

// Round 15
// 254.696 us; speedup vs baseline: 1.5159x; 1.5159x over previous
//
#include <hip/hip_runtime.h>
#include <hip/hip_fp16.h>

#define TPB 256
#define CAP 32          // fixed CSR slots per node (Poisson(16): P(deg>32) ~ 3e-5)
#define OVFCAP 65536    // overflow list capacity (expected usage ~tens)

typedef __attribute__((ext_vector_type(8))) short bf16x8;
typedef __attribute__((ext_vector_type(4))) float f32x4;

// ---------- fp32 -> bf16 hi/lo split ----------
__device__ inline void split1(float x, unsigned short& h, unsigned short& l) {
  unsigned xb = __float_as_uint(x);
  h = (unsigned short)(xb >> 16);
  float hf = __uint_as_float(xb & 0xFFFF0000u);
  float lf = x - hf;
  l = (unsigned short)(__float_as_uint(lf) >> 16);
}

__device__ inline void split4(const float4 v, ushort4& h, ushort4& l) {
  split1(v.x, h.x, l.x);
  split1(v.y, h.y, l.y);
  split1(v.z, h.z, l.z);
  split1(v.w, h.w, l.w);
}

// ---------- single-pass fixed-slot CSR fill (atomic floor: 1 RMW/edge) ----------
__global__ void k_fillslot(const int* __restrict__ src, const int* __restrict__ dst,
                           int* __restrict__ cnt, int* __restrict__ col2,
                           uint2* __restrict__ ovf, int* __restrict__ ovfn,
                           int E, int N) {
  const int g = blockIdx.x & 7;
  const int gb = blockIdx.x >> 3;
  const int gstride = (gridDim.x >> 3) * blockDim.x;
  const int lo = (int)(((long long)g * N) >> 3);
  const int hi = (int)(((long long)(g + 1) * N) >> 3);
  for (int e = gb * blockDim.x + threadIdx.x; e < E; e += gstride) {
    int d = __builtin_nontemporal_load(dst + e);
    if (d >= lo && d < hi) {
      int s = __builtin_nontemporal_load(src + e);
      int c = atomicAdd(cnt + d, 1);
      if (c < CAP) {
        col2[(size_t)d * CAP + c] = s;
      } else {
        int p = atomicAdd(ovfn, 1);
        if (p < OVFCAP) ovf[p] = make_uint2((unsigned)d, (unsigned)s);
      }
    }
  }
}

__global__ void k_dinv_from_cnt(const int* __restrict__ cnt, float* __restrict__ dinv, int N) {
  int i = blockIdx.x * blockDim.x + threadIdx.x;
  if (i < N) dinv[i] = rsqrtf((float)(cnt[i] + 1));
}

// ---------- W prep: both weights in one launch ----------
__global__ void k_prep_wt2(const float* __restrict__ W1, unsigned short* __restrict__ W1h,
                           unsigned short* __restrict__ W1l, int K1, int C1,
                           const float* __restrict__ W2, unsigned short* __restrict__ W2h,
                           unsigned short* __restrict__ W2l, int K2, int C2) {
  int i = blockIdx.x * blockDim.x + threadIdx.x;
  int n1 = K1 * C1;
  if (i < n1) {
    int k = i / C1, c = i % C1;
    unsigned short h, l;
    split1(W1[i], h, l);
    W1h[(size_t)c * K1 + k] = h;
    W1l[(size_t)c * K1 + k] = l;
  } else if (i < n1 + K2 * C2) {
    int ii = i - n1;
    int k = ii / C2, c = ii % C2;
    unsigned short h, l;
    split1(W2[ii], h, l);
    W2h[(size_t)c * K2 + k] = h;
    W2l[(size_t)c * K2 + k] = l;
  }
}

// ---------- MFMA GEMM: Y16 = fp16((X @ W) * dinv[row]) ----------
template<int COUT>
__launch_bounds__(512)
__global__ void k_gemm_mfma(const float* __restrict__ X, const unsigned short* __restrict__ Wh,
                            const unsigned short* __restrict__ Wl, const float* __restrict__ dinv,
                            __half* __restrict__ Y16, int N) {
  constexpr int K = 128;
  constexpr int BM = 128;
  constexpr int WCOL = COUT / 2;
  constexpr int NFRAG = WCOL / 16;
  __shared__ unsigned short Ah[BM * K], Al[BM * K];
  __shared__ unsigned short Wsh[COUT * K], Wsl[COUT * K];

  const int tid = threadIdx.x;
  const int rb = blockIdx.x * BM;

  {
    const uint4* gh = (const uint4*)Wh;
    const uint4* gl = (const uint4*)Wl;
    for (int i = tid; i < COUT * 16; i += 512) {
      int r = i >> 4, c = i & 15;
      int byte = r * 256 + ((c * 16) ^ ((r & 7) << 4));
      *(uint4*)((char*)Wsh + byte) = gh[i];
      *(uint4*)((char*)Wsl + byte) = gl[i];
    }
  }
  {
    for (int i = tid; i < BM * 32; i += 512) {
      int r = i >> 5, c4 = i & 31;
      int g = rb + r;
      if (g < N) {
        float4 v = ((const float4*)(X + (size_t)g * K))[c4];
        ushort4 h, l;
        split4(v, h, l);
        int byte = r * 256 + ((c4 * 8) ^ ((r & 7) << 4));
        *(ushort4*)((char*)Ah + byte) = h;
        *(ushort4*)((char*)Al + byte) = l;
      }
    }
  }
  __syncthreads();

  const int wid = tid >> 6, lane = tid & 63;
  const int wm = wid & 3;
  const int wn = wid >> 2;
  const int RB = wm * 32;
  const int CB = wn * WCOL;
  const int l15 = lane & 15, l4 = lane >> 4;
  const int xs = (l15 & 7) << 4;

  f32x4 acc[2][NFRAG];
  #pragma unroll
  for (int m = 0; m < 2; ++m)
    #pragma unroll
    for (int n = 0; n < NFRAG; ++n)
      acc[m][n] = (f32x4){0.f, 0.f, 0.f, 0.f};

  #pragma unroll
  for (int ks = 0; ks < 4; ++ks) {
    const int cbx = (ks * 64 + l4 * 16) ^ xs;
    bf16x8 a0h = *(const bf16x8*)((const char*)Ah + (RB + l15) * 256 + cbx);
    bf16x8 a0l = *(const bf16x8*)((const char*)Al + (RB + l15) * 256 + cbx);
    bf16x8 a1h = *(const bf16x8*)((const char*)Ah + (RB + 16 + l15) * 256 + cbx);
    bf16x8 a1l = *(const bf16x8*)((const char*)Al + (RB + 16 + l15) * 256 + cbx);
    #pragma unroll
    for (int n = 0; n < NFRAG; ++n) {
      const int wr = CB + n * 16 + l15;
      bf16x8 bh = *(const bf16x8*)((const char*)Wsh + wr * 256 + cbx);
      bf16x8 bl = *(const bf16x8*)((const char*)Wsl + wr * 256 + cbx);
      acc[0][n] = __builtin_amdgcn_mfma_f32_16x16x32_bf16(a0h, bh, acc[0][n], 0, 0, 0);
      acc[0][n] = __builtin_amdgcn_mfma_f32_16x16x32_bf16(a0h, bl, acc[0][n], 0, 0, 0);
      acc[0][n] = __builtin_amdgcn_mfma_f32_16x16x32_bf16(a0l, bh, acc[0][n], 0, 0, 0);
      acc[1][n] = __builtin_amdgcn_mfma_f32_16x16x32_bf16(a1h, bh, acc[1][n], 0, 0, 0);
      acc[1][n] = __builtin_amdgcn_mfma_f32_16x16x32_bf16(a1h, bl, acc[1][n], 0, 0, 0);
      acc[1][n] = __builtin_amdgcn_mfma_f32_16x16x32_bf16(a1l, bh, acc[1][n], 0, 0, 0);
    }
  }

  #pragma unroll
  for (int m = 0; m < 2; ++m) {
    #pragma unroll
    for (int q = 0; q < 4; ++q) {
      int row = rb + RB + m * 16 + l4 * 4 + q;
      if (row < N) {
        float dv = dinv[row];
        __half* yr = Y16 + (size_t)row * COUT + CB + l15;
        #pragma unroll
        for (int n = 0; n < NFRAG; ++n) yr[n * 16] = __float2half(acc[m][n][q] * dv);
      }
    }
  }
}

// ---------- vectorized aggregate: one WAVE per node; int4 index loads ----------
// Lane (i,j): one int4 load fetches 4 neighbor indices (slots 4j..4j+3), then
// owns those 4 16B gathers -> 1 index load + 4 gathers per round, no per-slot
// col dependency. Stale slots masked by clamping index to 0 with weight 0.
template<int C>
__launch_bounds__(256)
__global__ void k_aggv(const __half* __restrict__ hsh, const float* __restrict__ dinv,
                       const int* __restrict__ cnt, const int* __restrict__ col2,
                       const uint2* __restrict__ ovf, const int* __restrict__ ovfn,
                       const float* __restrict__ bias, float* __restrict__ out, int N) {
  constexpr int LPR = C / 8;           // lanes per row-slice: 16 (C=128) / 8 (C=64)
  constexpr int NG = 64 / LPR;         // neighbor groups: 4 / 8
  constexpr int SPR = 4 * NG;          // slots per round: 16 / 32
  constexpr int NR = CAP / SPR;        // rounds: 2 / 1
  const int node = blockIdx.x * 4 + (threadIdx.x >> 6);
  if (node >= N) return;
  const int lane = threadIdx.x & 63;
  const int i = lane % LPR;
  const int j = lane / LPR;
  const int deg = cnt[node];
  const int m = min(deg, CAP);
  const int4* cp4 = (const int4*)(col2 + (size_t)node * CAP);
  const size_t coloff = (size_t)i * 8;

  float acc[8];
  #pragma unroll
  for (int q = 0; q < 8; ++q) acc[q] = 0.f;

  #pragma unroll
  for (int r = 0; r < NR; ++r) {
    if (r * SPR < m) {                 // wave-uniform (m same across wave)
      int4 idx = cp4[r * NG + j];
      int s0 = r * SPR + 4 * j;
      bool ok0 = s0 + 0 < m, ok1 = s0 + 1 < m, ok2 = s0 + 2 < m, ok3 = s0 + 3 < m;
      int n0 = ok0 ? idx.x : 0;
      int n1 = ok1 ? idx.y : 0;
      int n2 = ok2 ? idx.z : 0;
      int n3 = ok3 ? idx.w : 0;
      uint4 v0 = *(const uint4*)((const char*)hsh + ((size_t)n0 * C + coloff) * 2);
      uint4 v1 = *(const uint4*)((const char*)hsh + ((size_t)n1 * C + coloff) * 2);
      uint4 v2 = *(const uint4*)((const char*)hsh + ((size_t)n2 * C + coloff) * 2);
      uint4 v3 = *(const uint4*)((const char*)hsh + ((size_t)n3 * C + coloff) * 2);
      float f0 = ok0 ? 1.f : 0.f, f1 = ok1 ? 1.f : 0.f;
      float f2 = ok2 ? 1.f : 0.f, f3 = ok3 ? 1.f : 0.f;
      const __half2* h0 = (const __half2*)&v0;
      const __half2* h1 = (const __half2*)&v1;
      const __half2* h2 = (const __half2*)&v2;
      const __half2* h3 = (const __half2*)&v3;
      #pragma unroll
      for (int q = 0; q < 4; ++q) {
        float2 a = __half22float2(h0[q]);
        float2 b = __half22float2(h1[q]);
        float2 c = __half22float2(h2[q]);
        float2 d = __half22float2(h3[q]);
        acc[2 * q]     = fmaf(f0, a.x, acc[2 * q]);
        acc[2 * q + 1] = fmaf(f0, a.y, acc[2 * q + 1]);
        acc[2 * q]     = fmaf(f1, b.x, acc[2 * q]);
        acc[2 * q + 1] = fmaf(f1, b.y, acc[2 * q + 1]);
        acc[2 * q]     = fmaf(f2, c.x, acc[2 * q]);
        acc[2 * q + 1] = fmaf(f2, c.y, acc[2 * q + 1]);
        acc[2 * q]     = fmaf(f3, d.x, acc[2 * q]);
        acc[2 * q + 1] = fmaf(f3, d.y, acc[2 * q + 1]);
      }
    }
  }

  // rare overflow path (deg > CAP): group j==0 scans the tiny overflow list
  if (deg > CAP && j == 0) {
    int on = min(*ovfn, (int)OVFCAP);
    for (int k = 0; k < on; ++k) {
      uint2 eo = ovf[k];
      if ((int)eo.x == node) {
        uint4 v = *(const uint4*)((const char*)hsh + ((size_t)eo.y * C + coloff) * 2);
        const __half2* h2 = (const __half2*)&v;
        #pragma unroll
        for (int q = 0; q < 4; ++q) {
          float2 a = __half22float2(h2[q]);
          acc[2 * q] += a.x;
          acc[2 * q + 1] += a.y;
        }
      }
    }
  }

  #pragma unroll
  for (int off = LPR; off < 64; off <<= 1)
    #pragma unroll
    for (int q = 0; q < 8; ++q)
      acc[q] += __shfl_xor(acc[q], off);

  if (j < 2) {
    const float dv = dinv[node];
    const int f4 = 2 * i + j;
    uint2 sh = *(const uint2*)((const char*)hsh + ((size_t)node * C + (size_t)f4 * 4) * 2);
    const __half2* shh = (const __half2*)&sh;
    float2 s01 = __half22float2(shh[0]);
    float2 s23 = __half22float2(shh[1]);
    float4 bb = ((const float4*)bias)[f4];
    float4 o;
    o.x = fmaxf(fmaf(dv, s01.x + acc[4 * j + 0], bb.x), 0.f);
    o.y = fmaxf(fmaf(dv, s01.y + acc[4 * j + 1], bb.y), 0.f);
    o.z = fmaxf(fmaf(dv, s23.x + acc[4 * j + 2], bb.z), 0.f);
    o.w = fmaxf(fmaf(dv, s23.y + acc[4 * j + 3], bb.w), 0.f);
    ((float4*)(out + (size_t)node * C))[f4] = o;
  }
}

// ---------- fallback (atomic scatter) kernels ----------
__global__ void k_fill1(float* __restrict__ p, int n) {
  int i = blockIdx.x * blockDim.x + threadIdx.x;
  if (i < n) p[i] = 1.0f;
}
__global__ void k_deg_scatter(const int* __restrict__ dst, float* __restrict__ deg, int E) {
  int e = blockIdx.x * blockDim.x + threadIdx.x;
  if (e < E) atomicAdd(deg + dst[e], 1.0f);
}
__global__ void k_rsqrt_inplace(float* __restrict__ p, int n) {
  int i = blockIdx.x * blockDim.x + threadIdx.x;
  if (i < n) p[i] = rsqrtf(p[i]);
}
template<int COUT>
__launch_bounds__(256)
__global__ void k_gemm128(const float* __restrict__ X, const float* __restrict__ W,
                          const float* __restrict__ dinv, float* __restrict__ Y, int N) {
  constexpr int K = 128;
  constexpr int CG = COUT / 8;
  constexpr int ROWS = 256 / CG;
  constexpr int XSTR = K + 4;
  __shared__ float Ws[K * COUT];
  __shared__ float Xs[ROWS * XSTR];
  const int tid = threadIdx.x;

  const float4* W4 = (const float4*)W;
  float4* Ws4 = (float4*)Ws;
  #pragma unroll
  for (int i = tid; i < K * COUT / 4; i += 256) Ws4[i] = W4[i];

  const int rb = blockIdx.x * ROWS;
  float4* Xs4 = (float4*)Xs;
  for (int i = tid; i < ROWS * (K / 4); i += 256) {
    int r = i / (K / 4), c = i % (K / 4);
    float4 v = make_float4(0.f, 0.f, 0.f, 0.f);
    if (rb + r < N) v = ((const float4*)(X + (size_t)(rb + r) * K))[c];
    Xs4[r * (XSTR / 4) + c] = v;
  }
  __syncthreads();

  const int lrow = tid / CG;
  const int cg = tid % CG;
  const int row = rb + lrow;
  float acc[8];
  #pragma unroll
  for (int jj = 0; jj < 8; ++jj) acc[jj] = 0.f;
  const float* xr = Xs + lrow * XSTR;
  #pragma unroll 4
  for (int k = 0; k < K; ++k) {
    float xv = xr[k];
    float4 w0 = Ws4[k * (COUT / 4) + cg * 2];
    float4 w1 = Ws4[k * (COUT / 4) + cg * 2 + 1];
    acc[0] = fmaf(xv, w0.x, acc[0]);
    acc[1] = fmaf(xv, w0.y, acc[1]);
    acc[2] = fmaf(xv, w0.z, acc[2]);
    acc[3] = fmaf(xv, w0.w, acc[3]);
    acc[4] = fmaf(xv, w1.x, acc[4]);
    acc[5] = fmaf(xv, w1.y, acc[5]);
    acc[6] = fmaf(xv, w1.z, acc[6]);
    acc[7] = fmaf(xv, w1.w, acc[7]);
  }
  if (row < N) {
    float ds = dinv[row];
    float4* y = (float4*)(Y + (size_t)row * COUT + cg * 8);
    y[0] = make_float4(acc[0] * ds, acc[1] * ds, acc[2] * ds, acc[3] * ds);
    y[1] = make_float4(acc[4] * ds, acc[5] * ds, acc[6] * ds, acc[7] * ds);
  }
}
template<int C>
__global__ void k_selfinit2(const float* __restrict__ hs, const float* __restrict__ dinv,
                            float* __restrict__ agg, int N) {
  int i = blockIdx.x * blockDim.x + threadIdx.x;
  int total = N * (C / 4);
  if (i >= total) return;
  int node = i / (C / 4);
  float di = dinv[node];
  float4 v = ((const float4*)hs)[i];
  ((float4*)agg)[i] = make_float4(v.x * di, v.y * di, v.z * di, v.w * di);
}
template<int C>
__global__ void k_scatter(const float* __restrict__ hs, const float* __restrict__ dinv,
                          const int* __restrict__ src, const int* __restrict__ dst,
                          float* __restrict__ agg, int E) {
  constexpr int LPE = C / 4;
  long long t = (long long)blockIdx.x * blockDim.x + threadIdx.x;
  int e = (int)(t / LPE);
  if (e >= E) return;
  int c4 = (int)(t % LPE);
  int s = src[e], d = dst[e];
  float nd = dinv[d];
  float4 v = ((const float4*)(hs + (size_t)s * C))[c4];
  float* a = agg + (size_t)d * C + (size_t)c4 * 4;
  atomicAdd(a + 0, v.x * nd);
  atomicAdd(a + 1, v.y * nd);
  atomicAdd(a + 2, v.z * nd);
  atomicAdd(a + 3, v.w * nd);
}
template<int C>
__global__ void k_relu_bias(const float* __restrict__ agg, const float* __restrict__ b,
                            float* __restrict__ out, int N) {
  int i = blockIdx.x * blockDim.x + threadIdx.x;
  int total = N * (C / 4);
  if (i >= total) return;
  int c4 = i % (C / 4);
  float4 bb = ((const float4*)b)[c4];
  float4 v = ((const float4*)agg)[i];
  v.x = fmaxf(v.x + bb.x, 0.f);
  v.y = fmaxf(v.y + bb.y, 0.f);
  v.z = fmaxf(v.z + bb.z, 0.f);
  v.w = fmaxf(v.w + bb.w, 0.f);
  ((float4*)out)[i] = v;
}

extern "C" void kernel_launch(void* const* d_in, const int* in_sizes, int n_in,
                              void* d_out, int out_size, void* d_ws, size_t ws_size,
                              hipStream_t stream) {
  const float* x  = (const float*)d_in[0];
  const int*   ei = (const int*)d_in[1];
  const float* W1 = (const float*)d_in[2];
  const float* b1 = (const float*)d_in[3];
  const float* W2 = (const float*)d_in[4];
  const float* b2 = (const float*)d_in[5];

  const int Cin = 128, Chid = 128, Cout2 = 64;
  const int N = in_sizes[0] / Cin;
  const int E = in_sizes[1] / 2;
  const int* src = ei;
  const int* dst = ei + E;
  float* out = (float*)d_out;
  (void)n_in; (void)out_size;

  const int nbN = (N + TPB - 1) / TPB;
  const int nbE = (E + TPB - 1) / TPB;

  auto align = [](size_t v) { return (v + 511) & ~(size_t)511; };
  char* ws = (char*)d_ws;
  size_t off = 0;
  float* dinv   = (float*)(ws + off); off += align((size_t)N * 4);
  int*   cnt    = (int*)(ws + off);   off += align((size_t)N * 4);
  unsigned short* wt1h = (unsigned short*)(ws + off); off += align((size_t)Cin * Chid * 2);
  unsigned short* wt1l = (unsigned short*)(ws + off); off += align((size_t)Cin * Chid * 2);
  unsigned short* wt2h = (unsigned short*)(ws + off); off += align((size_t)Chid * Cout2 * 2);
  unsigned short* wt2l = (unsigned short*)(ws + off); off += align((size_t)Chid * Cout2 * 2);
  int*   col2   = (int*)(ws + off);   off += align((size_t)N * CAP * 4);
  int*   ovfn   = (int*)(ws + off);   off += align((size_t)64);
  uint2* ovf    = (uint2*)(ws + off); off += align((size_t)OVFCAP * 8);
  float* B      = (float*)(ws + off); off += (size_t)N * Chid * 4;
  __half* H16   = (__half*)(ws + off); off += align((size_t)N * Chid * 2);

  const bool fast_ok = (off <= ws_size);

  if (fast_ok) {
    // ---- single-pass CSR build (cnt + col2 + overflow) ----
    hipMemsetAsync(cnt, 0, (size_t)N * 4, stream);
    hipMemsetAsync(ovfn, 0, 4, stream);
    k_fillslot<<<4096, TPB, 0, stream>>>(src, dst, cnt, col2, ovf, ovfn, E, N);
    k_dinv_from_cnt<<<nbN, TPB, 0, stream>>>(cnt, dinv, N);

    // ---- W prep (both weights, one launch) ----
    {
      int total = Cin * Chid + Chid * Cout2;
      k_prep_wt2<<<(total + TPB - 1) / TPB, TPB, 0, stream>>>(
          W1, wt1h, wt1l, Cin, Chid, W2, wt2h, wt2l, Chid, Cout2);
    }

    // ---- layer 1: 128 -> 128 ----
    k_gemm_mfma<128><<<(N + 127) / 128, 512, 0, stream>>>(x, wt1h, wt1l, dinv, H16, N);
    k_aggv<128><<<(N + 3) / 4, 256, 0, stream>>>(H16, dinv, cnt, col2, ovf, ovfn, b1, B, N);
    // ---- layer 2: 128 -> 64 ----
    k_gemm_mfma<64><<<(N + 127) / 128, 512, 0, stream>>>(B, wt2h, wt2l, dinv, H16, N);
    k_aggv<64><<<(N + 3) / 4, 256, 0, stream>>>(H16, dinv, cnt, col2, ovf, ovfn, b2, out, N);
  } else {
    // ---- fallback: atomic-scatter path ----
    size_t o2 = 0;
    float* dinvF = (float*)(ws + o2); o2 += align((size_t)N * 4);
    float* AF = (float*)(ws + o2);    o2 += (size_t)N * Chid * 4;
    float* BF = (float*)(ws + o2);

    k_fill1<<<nbN, TPB, 0, stream>>>(dinvF, N);
    k_deg_scatter<<<nbE, TPB, 0, stream>>>(dst, dinvF, E);
    k_rsqrt_inplace<<<nbN, TPB, 0, stream>>>(dinvF, N);

    k_gemm128<128><<<(N + 15) / 16, 256, 0, stream>>>(x, W1, dinvF, AF, N);
    k_selfinit2<128><<<(N * 32 + TPB - 1) / TPB, TPB, 0, stream>>>(AF, dinvF, BF, N);
    {
      long long total = (long long)E * 32;
      k_scatter<128><<<(int)((total + TPB - 1) / TPB), TPB, 0, stream>>>(AF, dinvF, src, dst, BF, E);
    }
    k_relu_bias<128><<<(N * 32 + TPB - 1) / TPB, TPB, 0, stream>>>(BF, b1, AF, N);

    k_gemm128<64><<<(N + 31) / 32, 256, 0, stream>>>(AF, W2, dinvF, BF, N);
    k_selfinit2<64><<<(N * 16 + TPB - 1) / TPB, TPB, 0, stream>>>(BF, dinvF, out, N);
    {
      long long total = (long long)E * 16;
      k_scatter<64><<<(int)((total + TPB - 1) / TPB), TPB, 0, stream>>>(BF, dinvF, src, dst, out, E);
    }
    k_relu_bias<64><<<(N * 16 + TPB - 1) / TPB, TPB, 0, stream>>>(out, b2, out, N);
  }
}

// Round 16
// 246.144 us; speedup vs baseline: 1.5686x; 1.0347x over previous
//
#include <hip/hip_runtime.h>
#include <hip/hip_fp16.h>
#include <type_traits>

#define TPB 256
#define CAP 32          // fixed CSR slots per node (Poisson(16): P(deg>32) ~ 3e-5)
#define OVFCAP 65536    // overflow list capacity (expected usage ~tens)

typedef __attribute__((ext_vector_type(8))) short bf16x8;
typedef __attribute__((ext_vector_type(4))) float f32x4;

// ---------- fp32 -> bf16 hi/lo split ----------
__device__ inline void split1(float x, unsigned short& h, unsigned short& l) {
  unsigned xb = __float_as_uint(x);
  h = (unsigned short)(xb >> 16);
  float hf = __uint_as_float(xb & 0xFFFF0000u);
  float lf = x - hf;
  l = (unsigned short)(__float_as_uint(lf) >> 16);
}

__device__ inline void split4(const float4 v, ushort4& h, ushort4& l) {
  split1(v.x, h.x, l.x);
  split1(v.y, h.y, l.y);
  split1(v.z, h.z, l.z);
  split1(v.w, h.w, l.w);
}

// ---------- single-pass fixed-slot CSR fill (atomic floor: 1 RMW/edge) ----------
__global__ void k_fillslot(const int* __restrict__ src, const int* __restrict__ dst,
                           int* __restrict__ cnt, int* __restrict__ col2,
                           uint2* __restrict__ ovf, int* __restrict__ ovfn,
                           int E, int N) {
  const int g = blockIdx.x & 7;
  const int gb = blockIdx.x >> 3;
  const int gstride = (gridDim.x >> 3) * blockDim.x;
  const int lo = (int)(((long long)g * N) >> 3);
  const int hi = (int)(((long long)(g + 1) * N) >> 3);
  for (int e = gb * blockDim.x + threadIdx.x; e < E; e += gstride) {
    int d = __builtin_nontemporal_load(dst + e);
    if (d >= lo && d < hi) {
      int s = __builtin_nontemporal_load(src + e);
      int c = atomicAdd(cnt + d, 1);
      if (c < CAP) {
        col2[(size_t)d * CAP + c] = s;
      } else {
        int p = atomicAdd(ovfn, 1);
        if (p < OVFCAP) ovf[p] = make_uint2((unsigned)d, (unsigned)s);
      }
    }
  }
}

__global__ void k_dinv_from_cnt(const int* __restrict__ cnt, float* __restrict__ dinv, int N) {
  int i = blockIdx.x * blockDim.x + threadIdx.x;
  if (i < N) dinv[i] = rsqrtf((float)(cnt[i] + 1));
}

// ---------- W prep: both weights in one launch ----------
__global__ void k_prep_wt2(const float* __restrict__ W1, unsigned short* __restrict__ W1h,
                           unsigned short* __restrict__ W1l, int K1, int C1,
                           const float* __restrict__ W2, unsigned short* __restrict__ W2h,
                           unsigned short* __restrict__ W2l, int K2, int C2) {
  int i = blockIdx.x * blockDim.x + threadIdx.x;
  int n1 = K1 * C1;
  if (i < n1) {
    int k = i / C1, c = i % C1;
    unsigned short h, l;
    split1(W1[i], h, l);
    W1h[(size_t)c * K1 + k] = h;
    W1l[(size_t)c * K1 + k] = l;
  } else if (i < n1 + K2 * C2) {
    int ii = i - n1;
    int k = ii / C2, c = ii % C2;
    unsigned short h, l;
    split1(W2[ii], h, l);
    W2h[(size_t)c * K2 + k] = h;
    W2l[(size_t)c * K2 + k] = l;
  }
}

// ---------- MFMA GEMM: Y16 = fp16((X @ W) * dinv[row]); TIN = float or __half ----------
template<int COUT, typename TIN>
__launch_bounds__(512)
__global__ void k_gemm_mfma(const TIN* __restrict__ X, const unsigned short* __restrict__ Wh,
                            const unsigned short* __restrict__ Wl, const float* __restrict__ dinv,
                            __half* __restrict__ Y16, int N) {
  constexpr int K = 128;
  constexpr int BM = 128;
  constexpr int WCOL = COUT / 2;
  constexpr int NFRAG = WCOL / 16;
  __shared__ unsigned short Ah[BM * K], Al[BM * K];
  __shared__ unsigned short Wsh[COUT * K], Wsl[COUT * K];

  const int tid = threadIdx.x;
  const int rb = blockIdx.x * BM;

  {
    const uint4* gh = (const uint4*)Wh;
    const uint4* gl = (const uint4*)Wl;
    for (int i = tid; i < COUT * 16; i += 512) {
      int r = i >> 4, c = i & 15;
      int byte = r * 256 + ((c * 16) ^ ((r & 7) << 4));
      *(uint4*)((char*)Wsh + byte) = gh[i];
      *(uint4*)((char*)Wsl + byte) = gl[i];
    }
  }
  if constexpr (std::is_same<TIN, float>::value) {
    for (int i = tid; i < BM * 32; i += 512) {
      int r = i >> 5, c4 = i & 31;
      int g = rb + r;
      if (g < N) {
        float4 v = ((const float4*)(X + (size_t)g * K))[c4];
        ushort4 h, l;
        split4(v, h, l);
        int byte = r * 256 + ((c4 * 8) ^ ((r & 7) << 4));
        *(ushort4*)((char*)Ah + byte) = h;
        *(ushort4*)((char*)Al + byte) = l;
      }
    }
  } else {
    // fp16 input: 16B chunk = 8 halves; convert -> split -> 16B LDS writes
    for (int i = tid; i < BM * 16; i += 512) {
      int r = i >> 4, c8 = i & 15;
      int g = rb + r;
      if (g < N) {
        uint4 v = ((const uint4*)(X + (size_t)g * K))[c8];
        const __half2* hh = (const __half2*)&v;
        ushort4 h0, l0, h1, l1;
        float2 f0 = __half22float2(hh[0]);
        float2 f1 = __half22float2(hh[1]);
        float2 f2 = __half22float2(hh[2]);
        float2 f3 = __half22float2(hh[3]);
        split4(make_float4(f0.x, f0.y, f1.x, f1.y), h0, l0);
        split4(make_float4(f2.x, f2.y, f3.x, f3.y), h1, l1);
        int byte = r * 256 + ((c8 * 16) ^ ((r & 7) << 4));
        *(ushort4*)((char*)Ah + byte) = h0;
        *(ushort4*)((char*)Ah + byte + 8) = h1;
        *(ushort4*)((char*)Al + byte) = l0;
        *(ushort4*)((char*)Al + byte + 8) = l1;
      }
    }
  }
  __syncthreads();

  const int wid = tid >> 6, lane = tid & 63;
  const int wm = wid & 3;
  const int wn = wid >> 2;
  const int RB = wm * 32;
  const int CB = wn * WCOL;
  const int l15 = lane & 15, l4 = lane >> 4;
  const int xs = (l15 & 7) << 4;

  f32x4 acc[2][NFRAG];
  #pragma unroll
  for (int m = 0; m < 2; ++m)
    #pragma unroll
    for (int n = 0; n < NFRAG; ++n)
      acc[m][n] = (f32x4){0.f, 0.f, 0.f, 0.f};

  #pragma unroll
  for (int ks = 0; ks < 4; ++ks) {
    const int cbx = (ks * 64 + l4 * 16) ^ xs;
    bf16x8 a0h = *(const bf16x8*)((const char*)Ah + (RB + l15) * 256 + cbx);
    bf16x8 a0l = *(const bf16x8*)((const char*)Al + (RB + l15) * 256 + cbx);
    bf16x8 a1h = *(const bf16x8*)((const char*)Ah + (RB + 16 + l15) * 256 + cbx);
    bf16x8 a1l = *(const bf16x8*)((const char*)Al + (RB + 16 + l15) * 256 + cbx);
    #pragma unroll
    for (int n = 0; n < NFRAG; ++n) {
      const int wr = CB + n * 16 + l15;
      bf16x8 bh = *(const bf16x8*)((const char*)Wsh + wr * 256 + cbx);
      bf16x8 bl = *(const bf16x8*)((const char*)Wsl + wr * 256 + cbx);
      acc[0][n] = __builtin_amdgcn_mfma_f32_16x16x32_bf16(a0h, bh, acc[0][n], 0, 0, 0);
      acc[0][n] = __builtin_amdgcn_mfma_f32_16x16x32_bf16(a0h, bl, acc[0][n], 0, 0, 0);
      acc[0][n] = __builtin_amdgcn_mfma_f32_16x16x32_bf16(a0l, bh, acc[0][n], 0, 0, 0);
      acc[1][n] = __builtin_amdgcn_mfma_f32_16x16x32_bf16(a1h, bh, acc[1][n], 0, 0, 0);
      acc[1][n] = __builtin_amdgcn_mfma_f32_16x16x32_bf16(a1h, bl, acc[1][n], 0, 0, 0);
      acc[1][n] = __builtin_amdgcn_mfma_f32_16x16x32_bf16(a1l, bh, acc[1][n], 0, 0, 0);
    }
  }

  #pragma unroll
  for (int m = 0; m < 2; ++m) {
    #pragma unroll
    for (int q = 0; q < 4; ++q) {
      int row = rb + RB + m * 16 + l4 * 4 + q;
      if (row < N) {
        float dv = dinv[row];
        __half* yr = Y16 + (size_t)row * COUT + CB + l15;
        #pragma unroll
        for (int n = 0; n < NFRAG; ++n) yr[n * 16] = __float2half(acc[m][n][q] * dv);
      }
    }
  }
}

// ---------- vectorized aggregate: one WAVE per node; int4 index loads ----------
// OUT = __half (inter-layer activation) or float (final output).
template<int C, typename OUT>
__launch_bounds__(256)
__global__ void k_aggv(const __half* __restrict__ hsh, const float* __restrict__ dinv,
                       const int* __restrict__ cnt, const int* __restrict__ col2,
                       const uint2* __restrict__ ovf, const int* __restrict__ ovfn,
                       const float* __restrict__ bias, OUT* __restrict__ out, int N) {
  constexpr int LPR = C / 8;           // lanes per row-slice: 16 (C=128) / 8 (C=64)
  constexpr int NG = 64 / LPR;         // neighbor groups: 4 / 8
  constexpr int SPR = 4 * NG;          // slots per round: 16 / 32
  constexpr int NR = CAP / SPR;        // rounds: 2 / 1
  const int node = blockIdx.x * 4 + (threadIdx.x >> 6);
  if (node >= N) return;
  const int lane = threadIdx.x & 63;
  const int i = lane % LPR;
  const int j = lane / LPR;
  const int deg = cnt[node];
  const int m = min(deg, CAP);
  const int4* cp4 = (const int4*)(col2 + (size_t)node * CAP);
  const size_t coloff = (size_t)i * 8;

  float acc[8];
  #pragma unroll
  for (int q = 0; q < 8; ++q) acc[q] = 0.f;

  #pragma unroll
  for (int r = 0; r < NR; ++r) {
    if (r * SPR < m) {                 // wave-uniform (m same across wave)
      int4 idx = cp4[r * NG + j];
      int s0 = r * SPR + 4 * j;
      bool ok0 = s0 + 0 < m, ok1 = s0 + 1 < m, ok2 = s0 + 2 < m, ok3 = s0 + 3 < m;
      int n0 = ok0 ? idx.x : 0;
      int n1 = ok1 ? idx.y : 0;
      int n2 = ok2 ? idx.z : 0;
      int n3 = ok3 ? idx.w : 0;
      uint4 v0 = *(const uint4*)((const char*)hsh + ((size_t)n0 * C + coloff) * 2);
      uint4 v1 = *(const uint4*)((const char*)hsh + ((size_t)n1 * C + coloff) * 2);
      uint4 v2 = *(const uint4*)((const char*)hsh + ((size_t)n2 * C + coloff) * 2);
      uint4 v3 = *(const uint4*)((const char*)hsh + ((size_t)n3 * C + coloff) * 2);
      float f0 = ok0 ? 1.f : 0.f, f1 = ok1 ? 1.f : 0.f;
      float f2 = ok2 ? 1.f : 0.f, f3 = ok3 ? 1.f : 0.f;
      const __half2* h0 = (const __half2*)&v0;
      const __half2* h1 = (const __half2*)&v1;
      const __half2* h2 = (const __half2*)&v2;
      const __half2* h3 = (const __half2*)&v3;
      #pragma unroll
      for (int q = 0; q < 4; ++q) {
        float2 a = __half22float2(h0[q]);
        float2 b = __half22float2(h1[q]);
        float2 c = __half22float2(h2[q]);
        float2 d = __half22float2(h3[q]);
        acc[2 * q]     = fmaf(f0, a.x, acc[2 * q]);
        acc[2 * q + 1] = fmaf(f0, a.y, acc[2 * q + 1]);
        acc[2 * q]     = fmaf(f1, b.x, acc[2 * q]);
        acc[2 * q + 1] = fmaf(f1, b.y, acc[2 * q + 1]);
        acc[2 * q]     = fmaf(f2, c.x, acc[2 * q]);
        acc[2 * q + 1] = fmaf(f2, c.y, acc[2 * q + 1]);
        acc[2 * q]     = fmaf(f3, d.x, acc[2 * q]);
        acc[2 * q + 1] = fmaf(f3, d.y, acc[2 * q + 1]);
      }
    }
  }

  // rare overflow path (deg > CAP): group j==0 scans the tiny overflow list
  if (deg > CAP && j == 0) {
    int on = min(*ovfn, (int)OVFCAP);
    for (int k = 0; k < on; ++k) {
      uint2 eo = ovf[k];
      if ((int)eo.x == node) {
        uint4 v = *(const uint4*)((const char*)hsh + ((size_t)eo.y * C + coloff) * 2);
        const __half2* h2 = (const __half2*)&v;
        #pragma unroll
        for (int q = 0; q < 4; ++q) {
          float2 a = __half22float2(h2[q]);
          acc[2 * q] += a.x;
          acc[2 * q + 1] += a.y;
        }
      }
    }
  }

  #pragma unroll
  for (int off = LPR; off < 64; off <<= 1)
    #pragma unroll
    for (int q = 0; q < 8; ++q)
      acc[q] += __shfl_xor(acc[q], off);

  if (j < 2) {
    const float dv = dinv[node];
    const int f4 = 2 * i + j;
    uint2 sh = *(const uint2*)((const char*)hsh + ((size_t)node * C + (size_t)f4 * 4) * 2);
    const __half2* shh = (const __half2*)&sh;
    float2 s01 = __half22float2(shh[0]);
    float2 s23 = __half22float2(shh[1]);
    float4 bb = ((const float4*)bias)[f4];
    float4 o;
    o.x = fmaxf(fmaf(dv, s01.x + acc[4 * j + 0], bb.x), 0.f);
    o.y = fmaxf(fmaf(dv, s01.y + acc[4 * j + 1], bb.y), 0.f);
    o.z = fmaxf(fmaf(dv, s23.x + acc[4 * j + 2], bb.z), 0.f);
    o.w = fmaxf(fmaf(dv, s23.y + acc[4 * j + 3], bb.w), 0.f);
    if constexpr (std::is_same<OUT, __half>::value) {
      union { __half2 h2[2]; uint2 u; } pk;
      pk.h2[0] = __float22half2_rn(make_float2(o.x, o.y));
      pk.h2[1] = __float22half2_rn(make_float2(o.z, o.w));
      *(uint2*)((char*)out + ((size_t)node * C + (size_t)f4 * 4) * 2) = pk.u;
    } else {
      ((float4*)(out + (size_t)node * C))[f4] = o;
    }
  }
}

// ---------- fallback (atomic scatter) kernels ----------
__global__ void k_fill1(float* __restrict__ p, int n) {
  int i = blockIdx.x * blockDim.x + threadIdx.x;
  if (i < n) p[i] = 1.0f;
}
__global__ void k_deg_scatter(const int* __restrict__ dst, float* __restrict__ deg, int E) {
  int e = blockIdx.x * blockDim.x + threadIdx.x;
  if (e < E) atomicAdd(deg + dst[e], 1.0f);
}
__global__ void k_rsqrt_inplace(float* __restrict__ p, int n) {
  int i = blockIdx.x * blockDim.x + threadIdx.x;
  if (i < n) p[i] = rsqrtf(p[i]);
}
template<int COUT>
__launch_bounds__(256)
__global__ void k_gemm128(const float* __restrict__ X, const float* __restrict__ W,
                          const float* __restrict__ dinv, float* __restrict__ Y, int N) {
  constexpr int K = 128;
  constexpr int CG = COUT / 8;
  constexpr int ROWS = 256 / CG;
  constexpr int XSTR = K + 4;
  __shared__ float Ws[K * COUT];
  __shared__ float Xs[ROWS * XSTR];
  const int tid = threadIdx.x;

  const float4* W4 = (const float4*)W;
  float4* Ws4 = (float4*)Ws;
  #pragma unroll
  for (int i = tid; i < K * COUT / 4; i += 256) Ws4[i] = W4[i];

  const int rb = blockIdx.x * ROWS;
  float4* Xs4 = (float4*)Xs;
  for (int i = tid; i < ROWS * (K / 4); i += 256) {
    int r = i / (K / 4), c = i % (K / 4);
    float4 v = make_float4(0.f, 0.f, 0.f, 0.f);
    if (rb + r < N) v = ((const float4*)(X + (size_t)(rb + r) * K))[c];
    Xs4[r * (XSTR / 4) + c] = v;
  }
  __syncthreads();

  const int lrow = tid / CG;
  const int cg = tid % CG;
  const int row = rb + lrow;
  float acc[8];
  #pragma unroll
  for (int jj = 0; jj < 8; ++jj) acc[jj] = 0.f;
  const float* xr = Xs + lrow * XSTR;
  #pragma unroll 4
  for (int k = 0; k < K; ++k) {
    float xv = xr[k];
    float4 w0 = Ws4[k * (COUT / 4) + cg * 2];
    float4 w1 = Ws4[k * (COUT / 4) + cg * 2 + 1];
    acc[0] = fmaf(xv, w0.x, acc[0]);
    acc[1] = fmaf(xv, w0.y, acc[1]);
    acc[2] = fmaf(xv, w0.z, acc[2]);
    acc[3] = fmaf(xv, w0.w, acc[3]);
    acc[4] = fmaf(xv, w1.x, acc[4]);
    acc[5] = fmaf(xv, w1.y, acc[5]);
    acc[6] = fmaf(xv, w1.z, acc[6]);
    acc[7] = fmaf(xv, w1.w, acc[7]);
  }
  if (row < N) {
    float ds = dinv[row];
    float4* y = (float4*)(Y + (size_t)row * COUT + cg * 8);
    y[0] = make_float4(acc[0] * ds, acc[1] * ds, acc[2] * ds, acc[3] * ds);
    y[1] = make_float4(acc[4] * ds, acc[5] * ds, acc[6] * ds, acc[7] * ds);
  }
}
template<int C>
__global__ void k_selfinit2(const float* __restrict__ hs, const float* __restrict__ dinv,
                            float* __restrict__ agg, int N) {
  int i = blockIdx.x * blockDim.x + threadIdx.x;
  int total = N * (C / 4);
  if (i >= total) return;
  int node = i / (C / 4);
  float di = dinv[node];
  float4 v = ((const float4*)hs)[i];
  ((float4*)agg)[i] = make_float4(v.x * di, v.y * di, v.z * di, v.w * di);
}
template<int C>
__global__ void k_scatter(const float* __restrict__ hs, const float* __restrict__ dinv,
                          const int* __restrict__ src, const int* __restrict__ dst,
                          float* __restrict__ agg, int E) {
  constexpr int LPE = C / 4;
  long long t = (long long)blockIdx.x * blockDim.x + threadIdx.x;
  int e = (int)(t / LPE);
  if (e >= E) return;
  int c4 = (int)(t % LPE);
  int s = src[e], d = dst[e];
  float nd = dinv[d];
  float4 v = ((const float4*)(hs + (size_t)s * C))[c4];
  float* a = agg + (size_t)d * C + (size_t)c4 * 4;
  atomicAdd(a + 0, v.x * nd);
  atomicAdd(a + 1, v.y * nd);
  atomicAdd(a + 2, v.z * nd);
  atomicAdd(a + 3, v.w * nd);
}
template<int C>
__global__ void k_relu_bias(const float* __restrict__ agg, const float* __restrict__ b,
                            float* __restrict__ out, int N) {
  int i = blockIdx.x * blockDim.x + threadIdx.x;
  int total = N * (C / 4);
  if (i >= total) return;
  int c4 = i % (C / 4);
  float4 bb = ((const float4*)b)[c4];
  float4 v = ((const float4*)agg)[i];
  v.x = fmaxf(v.x + bb.x, 0.f);
  v.y = fmaxf(v.y + bb.y, 0.f);
  v.z = fmaxf(v.z + bb.z, 0.f);
  v.w = fmaxf(v.w + bb.w, 0.f);
  ((float4*)out)[i] = v;
}

extern "C" void kernel_launch(void* const* d_in, const int* in_sizes, int n_in,
                              void* d_out, int out_size, void* d_ws, size_t ws_size,
                              hipStream_t stream) {
  const float* x  = (const float*)d_in[0];
  const int*   ei = (const int*)d_in[1];
  const float* W1 = (const float*)d_in[2];
  const float* b1 = (const float*)d_in[3];
  const float* W2 = (const float*)d_in[4];
  const float* b2 = (const float*)d_in[5];

  const int Cin = 128, Chid = 128, Cout2 = 64;
  const int N = in_sizes[0] / Cin;
  const int E = in_sizes[1] / 2;
  const int* src = ei;
  const int* dst = ei + E;
  float* out = (float*)d_out;
  (void)n_in; (void)out_size;

  const int nbN = (N + TPB - 1) / TPB;
  const int nbE = (E + TPB - 1) / TPB;

  auto align = [](size_t v) { return (v + 511) & ~(size_t)511; };
  char* ws = (char*)d_ws;
  size_t off = 0;
  float* dinv   = (float*)(ws + off); off += align((size_t)N * 4);
  int*   cnt    = (int*)(ws + off);   off += align((size_t)N * 4);
  unsigned short* wt1h = (unsigned short*)(ws + off); off += align((size_t)Cin * Chid * 2);
  unsigned short* wt1l = (unsigned short*)(ws + off); off += align((size_t)Cin * Chid * 2);
  unsigned short* wt2h = (unsigned short*)(ws + off); off += align((size_t)Chid * Cout2 * 2);
  unsigned short* wt2l = (unsigned short*)(ws + off); off += align((size_t)Chid * Cout2 * 2);
  int*   col2   = (int*)(ws + off);   off += align((size_t)N * CAP * 4);
  int*   ovfn   = (int*)(ws + off);   off += align((size_t)64);
  uint2* ovf    = (uint2*)(ws + off); off += align((size_t)OVFCAP * 8);
  __half* B16   = (__half*)(ws + off); off += align((size_t)N * Chid * 2);
  __half* H16   = (__half*)(ws + off); off += align((size_t)N * Chid * 2);
  const size_t off_fast = off;
  const bool fast_ok = (off_fast <= ws_size);

  if (fast_ok) {
    // ---- single-pass CSR build (cnt + col2 + overflow) ----
    hipMemsetAsync(cnt, 0, (size_t)N * 4, stream);
    hipMemsetAsync(ovfn, 0, 4, stream);
    k_fillslot<<<4096, TPB, 0, stream>>>(src, dst, cnt, col2, ovf, ovfn, E, N);
    k_dinv_from_cnt<<<nbN, TPB, 0, stream>>>(cnt, dinv, N);

    // ---- W prep (both weights, one launch) ----
    {
      int total = Cin * Chid + Chid * Cout2;
      k_prep_wt2<<<(total + TPB - 1) / TPB, TPB, 0, stream>>>(
          W1, wt1h, wt1l, Cin, Chid, W2, wt2h, wt2l, Chid, Cout2);
    }

    // ---- layer 1: 128 -> 128 (all-fp16 intermediates) ----
    k_gemm_mfma<128, float><<<(N + 127) / 128, 512, 0, stream>>>(x, wt1h, wt1l, dinv, H16, N);
    k_aggv<128, __half><<<(N + 3) / 4, 256, 0, stream>>>(H16, dinv, cnt, col2, ovf, ovfn, b1, B16, N);
    // ---- layer 2: 128 -> 64 ----
    k_gemm_mfma<64, __half><<<(N + 127) / 128, 512, 0, stream>>>(B16, wt2h, wt2l, dinv, H16, N);
    k_aggv<64, float><<<(N + 3) / 4, 256, 0, stream>>>(H16, dinv, cnt, col2, ovf, ovfn, b2, out, N);
  } else {
    // ---- fallback: atomic-scatter path ----
    size_t o2 = 0;
    float* dinvF = (float*)(ws + o2); o2 += align((size_t)N * 4);
    float* AF = (float*)(ws + o2);    o2 += (size_t)N * Chid * 4;
    float* BF = (float*)(ws + o2);

    k_fill1<<<nbN, TPB, 0, stream>>>(dinvF, N);
    k_deg_scatter<<<nbE, TPB, 0, stream>>>(dst, dinvF, E);
    k_rsqrt_inplace<<<nbN, TPB, 0, stream>>>(dinvF, N);

    k_gemm128<128><<<(N + 15) / 16, 256, 0, stream>>>(x, W1, dinvF, AF, N);
    k_selfinit2<128><<<(N * 32 + TPB - 1) / TPB, TPB, 0, stream>>>(AF, dinvF, BF, N);
    {
      long long total = (long long)E * 32;
      k_scatter<128><<<(int)((total + TPB - 1) / TPB), TPB, 0, stream>>>(AF, dinvF, src, dst, BF, E);
    }
    k_relu_bias<128><<<(N * 32 + TPB - 1) / TPB, TPB, 0, stream>>>(BF, b1, AF, N);

    k_gemm128<64><<<(N + 31) / 32, 256, 0, stream>>>(AF, W2, dinvF, BF, N);
    k_selfinit2<64><<<(N * 16 + TPB - 1) / TPB, TPB, 0, stream>>>(BF, dinvF, out, N);
    {
      long long total = (long long)E * 16;
      k_scatter<64><<<(int)((total + TPB - 1) / TPB), TPB, 0, stream>>>(BF, dinvF, src, dst, out, E);
    }
    k_relu_bias<64><<<(N * 16 + TPB - 1) / TPB, TPB, 0, stream>>>(out, b2, out, N);
  }
}